// Round 5
// baseline (134.634 us; speedup 1.0000x reference)
//
#include <hip/hip_runtime.h>
#include <math.h>

#define HSZ 2048
#define OSZ 1024
#define NGATE 8192  // 4*HSZ

typedef float f32x4 __attribute__((ext_vector_type(4)));

__device__ __forceinline__ float wave_reduce_sum(float v) {
    #pragma unroll
    for (int off = 32; off > 0; off >>= 1)
        v += __shfl_down(v, off, 64);
    return v;
}

struct PreArgs {
    const float* x;      // 1024
    const float* h0; const float* h1; const float* h2; const float* h3; const float* h4;
    const float* Wih1;   // 8192x1024
    const float* W0; const float* W1; const float* W2; const float* W3; const float* W4; // Whh_k 8192x2048
    const float* bi0; const float* bi1; const float* bi2; const float* bi3; const float* bi4;
    const float* bh0; const float* bh1; const float* bh2; const float* bh3; const float* bh4;
    float* pre;          // ws, 5*8192
};

#define DOT4(W, H) ((W).x * (H).x + (W).y * (H).y + (W).z * (H).z + (W).w * (H).w)

// Issue one 4KB weight chunk (4 x dwordx4 per lane) fire-and-forget.
// ONLY weight loads exist in the pipeline region, so vmcnt counts are exact.
#define WISSUE(J, BUF) do {                                                    \
    asm volatile(                                                              \
        "global_load_dwordx4 %0, %4, off\n\t"                                  \
        "global_load_dwordx4 %1, %4, off offset:1024\n\t"                      \
        "global_load_dwordx4 %2, %4, off offset:2048\n\t"                      \
        "global_load_dwordx4 %3, %4, off offset:3072\n\t"                      \
        : "=&v"(BUF[0]), "=&v"(BUF[1]), "=&v"(BUF[2]), "=&v"(BUF[3])           \
        : "v"(wsrc##J));                                                       \
} while (0)

// Counted wait + scheduling fence (rule 18).
#define VWAIT(N) do {                                                          \
    asm volatile("s_waitcnt vmcnt(" #N ")" ::: "memory");                      \
    __builtin_amdgcn_sched_barrier(0);                                         \
} while (0)

#define LAYER_OF(J) ((J) == 0 ? 0 : ((J) - 1) >> 1)
#define HOFF(J) ((J) == 0 ? 0 : (1024 + (((J) - 1) >> 1) * 2048 + (((J) - 1) & 1) * 1024))

#define WSTEP(J, NW, BUF) do {                                                 \
    VWAIT(NW);                                                                 \
    const f32x4* hp_ = (const f32x4*)(sh + HOFF(J) + lo);                      \
    float s_ = DOT4(BUF[0], hp_[0])  + DOT4(BUF[1], hp_[64]) +                 \
               DOT4(BUF[2], hp_[128]) + DOT4(BUF[3], hp_[192]);                \
    ls[LAYER_OF(J)] += s_;                                                     \
} while (0)

// 1024 blocks x 512 threads; wave ww handles gate row g = blockIdx*8+ww for all
// 5 layers. x + h staged in LDS once per block; ONLY cold weight bytes go
// through the global-load path (frees per-CU outstanding-line slots).
__global__ __launch_bounds__(512) void k_pre(PreArgs a) {
    __shared__ float sh[11264];  // x[1024] + h[5][2048] = 44 KB
    const int t    = threadIdx.x;
    const int g    = blockIdx.x * 8 + (t >> 6);  // 0..8191
    const int lane = t & 63;
    const int lo   = lane * 4;   // float offset of this lane's 16B slice

    const float* Whh[5] = {a.W0, a.W1, a.W2, a.W3, a.W4};
    const float* hs[5]  = {a.h0, a.h1, a.h2, a.h3, a.h4};
    const float* bi[5]  = {a.bi0, a.bi1, a.bi2, a.bi3, a.bi4};
    const float* bh[5]  = {a.bh0, a.bh1, a.bh2, a.bh3, a.bh4};

    // stage x + h into LDS (compiler loads; drained by the barrier)
    {
        float4* s4 = (float4*)sh;
        if (t < 256) s4[t] = ((const float4*)a.x)[t];
        #pragma unroll
        for (int k = 0; k < 5; ++k)
            ((float4*)(sh + 1024 + k * 2048))[t] = ((const float4*)hs[k])[t];
    }

    // biases now, so no compiler global loads remain in the pipeline region
    float bb[5];
    #pragma unroll
    for (int k = 0; k < 5; ++k) bb[k] = bi[k][g] + bh[k][g];

    __syncthreads();
    VWAIT(0);  // clean vm state before exact counting

    const size_t rw = (size_t)g * HSZ;
    const float* wsrc0  = a.Wih1 + (size_t)g * OSZ + lo;
    const float* wsrc1  = Whh[0] + rw + 0    + lo;
    const float* wsrc2  = Whh[0] + rw + 1024 + lo;
    const float* wsrc3  = Whh[1] + rw + 0    + lo;
    const float* wsrc4  = Whh[1] + rw + 1024 + lo;
    const float* wsrc5  = Whh[2] + rw + 0    + lo;
    const float* wsrc6  = Whh[2] + rw + 1024 + lo;
    const float* wsrc7  = Whh[3] + rw + 0    + lo;
    const float* wsrc8  = Whh[3] + rw + 1024 + lo;
    const float* wsrc9  = Whh[4] + rw + 0    + lo;
    const float* wsrc10 = Whh[4] + rw + 1024 + lo;

    float ls[5] = {0.f, 0.f, 0.f, 0.f, 0.f};
    f32x4 Wa[4], Wb[4], Wc[4], Wd[4];

    WISSUE(0, Wa); WISSUE(1, Wb); WISSUE(2, Wc); WISSUE(3, Wd);
    WSTEP(0, 12, Wa);  WISSUE(4, Wa);
    WSTEP(1, 12, Wb);  WISSUE(5, Wb);
    WSTEP(2, 12, Wc);  WISSUE(6, Wc);
    WSTEP(3, 12, Wd);  WISSUE(7, Wd);
    WSTEP(4, 12, Wa);  WISSUE(8, Wa);
    WSTEP(5, 12, Wb);  WISSUE(9, Wb);
    WSTEP(6, 12, Wc);  WISSUE(10, Wc);
    WSTEP(7, 12, Wd);
    WSTEP(8, 8, Wa);
    WSTEP(9, 4, Wb);
    WSTEP(10, 0, Wc);

    // interleaved wave reductions (5 independent chains share the 6 steps)
    #pragma unroll
    for (int off = 32; off > 0; off >>= 1) {
        #pragma unroll
        for (int k = 0; k < 5; ++k)
            ls[k] += __shfl_down(ls[k], off, 64);
    }
    if (lane == 0) {
        #pragma unroll
        for (int k = 0; k < 5; ++k)
            a.pre[k * NGATE + g] = ls[k] + bb[k];
    }
}

// gates[g] += Wih[g,:] · (ya [+ yb]) — one wave per row, 8192 rows
__global__ __launch_bounds__(256) void k_gatex(const float* __restrict__ Wih,
                                               const float* __restrict__ ya,
                                               const float* __restrict__ yb,
                                               float* __restrict__ gates) {
    const int w    = blockIdx.x * 4 + (threadIdx.x >> 6);  // 0..8191
    const int lane = threadIdx.x & 63;
    const float4* Wrow = (const float4*)(Wih + (size_t)w * OSZ);
    const float4* A = (const float4*)ya;
    const float4* B = (const float4*)yb;
    float sum = 0.f;
    #pragma unroll
    for (int it = 0; it < 4; ++it) {
        float4 wv = Wrow[it * 64 + lane];
        float4 av = A[it * 64 + lane];
        if (B) {
            float4 bv = B[it * 64 + lane];
            av.x += bv.x; av.y += bv.y; av.z += bv.z; av.w += bv.w;
        }
        sum += wv.x * av.x + wv.y * av.y + wv.z * av.z + wv.w * av.w;
    }
    sum = wave_reduce_sum(sum);
    if (lane == 0)
        gates[w] += sum;
}

// LSTM cell elementwise: 2048 threads
__global__ __launch_bounds__(256) void k_cell(const float* __restrict__ gates,
                                              const float* __restrict__ c_in,
                                              float* __restrict__ hn,
                                              float* __restrict__ cn) {
    const int j = blockIdx.x * 256 + threadIdx.x;  // grid 8 -> 0..2047
    float gi = gates[j];
    float gf = gates[HSZ + j];
    float gg = gates[2 * HSZ + j];
    float go = gates[3 * HSZ + j];
    float i = 1.f / (1.f + expf(-gi));
    float f = 1.f / (1.f + expf(-gf));
    float g = tanhf(gg);
    float o = 1.f / (1.f + expf(-go));
    float c = c_in[j];
    float cnew = f * c + i * g;
    float hnew = o * tanhf(cnew);
    cn[j] = cnew;
    hn[j] = hnew;
}

// y[j] = Wout[j,:] · h + bout[j] — one wave per row, 1024 rows
__global__ __launch_bounds__(256) void k_head(const float* __restrict__ Wout,
                                              const float* __restrict__ bout,
                                              const float* __restrict__ h,
                                              float* __restrict__ y) {
    const int w    = blockIdx.x * 4 + (threadIdx.x >> 6);  // 0..1023
    const int lane = threadIdx.x & 63;
    const float4* Wrow = (const float4*)(Wout + (size_t)w * HSZ);
    const float4* hv   = (const float4*)h;
    float sum = 0.f;
    #pragma unroll
    for (int it = 0; it < 8; ++it) {
        float4 wv = Wrow[it * 64 + lane];
        float4 h4 = hv[it * 64 + lane];
        sum += wv.x * h4.x + wv.y * h4.y + wv.z * h4.z + wv.w * h4.w;
    }
    sum = wave_reduce_sum(sum);
    if (lane == 0)
        y[w] = sum + bout[w];
}

// softmax over 1024 logits, single block of 1024 threads
__global__ __launch_bounds__(1024) void k_softmax(const float* __restrict__ logits,
                                                  float* __restrict__ out) {
    __shared__ float sm[16];
    __shared__ float ss[16];
    const int t = threadIdx.x;
    const int lane = t & 63;
    const int wid = t >> 6;
    float v = logits[t];
    float m = v;
    #pragma unroll
    for (int off = 32; off > 0; off >>= 1)
        m = fmaxf(m, __shfl_down(m, off, 64));
    if (lane == 0) sm[wid] = m;
    __syncthreads();
    if (t == 0) {
        float mm = sm[0];
        for (int i = 1; i < 16; ++i) mm = fmaxf(mm, sm[i]);
        sm[0] = mm;
    }
    __syncthreads();
    m = sm[0];
    float e = expf(v - m);
    float s = wave_reduce_sum(e);
    if (lane == 0) ss[wid] = s;
    __syncthreads();
    if (t == 0) {
        float tt = 0.f;
        for (int i = 0; i < 16; ++i) tt += ss[i];
        ss[0] = tt;
    }
    __syncthreads();
    out[t] = e / ss[0];
}

extern "C" void kernel_launch(void* const* d_in, const int* in_sizes, int n_in,
                              void* d_out, int out_size, void* d_ws, size_t ws_size,
                              hipStream_t stream) {
    const float* x = (const float*)d_in[0];
    const float* h[5]; const float* c[5];
    for (int k = 0; k < 5; ++k) {
        h[k] = (const float*)d_in[1 + 2 * k];
        c[k] = (const float*)d_in[2 + 2 * k];
    }
    const float* Wih[5]; const float* Whh[5]; const float* bih[5]; const float* bhh[5];
    for (int k = 0; k < 5; ++k) {
        Wih[k] = (const float*)d_in[11 + 4 * k];
        Whh[k] = (const float*)d_in[12 + 4 * k];
        bih[k] = (const float*)d_in[13 + 4 * k];
        bhh[k] = (const float*)d_in[14 + 4 * k];
    }
    const float* Wout = (const float*)d_in[31];
    const float* bout = (const float*)d_in[32];

    float* out = (float*)d_out;              // [0,1024) softmax out
    float* hn[5]; float* cn[5];
    for (int k = 0; k < 5; ++k) {
        hn[k] = out + 1024 + k * 4096;
        cn[k] = hn[k] + 2048;
    }

    float* ws  = (float*)d_ws;
    float* pre = ws;             // 5*8192 floats
    float* y   = ws + 5 * NGATE; // 5*1024 floats

    PreArgs pa;
    pa.x = x;
    pa.h0 = h[0]; pa.h1 = h[1]; pa.h2 = h[2]; pa.h3 = h[3]; pa.h4 = h[4];
    pa.Wih1 = Wih[0];
    pa.W0 = Whh[0]; pa.W1 = Whh[1]; pa.W2 = Whh[2]; pa.W3 = Whh[3]; pa.W4 = Whh[4];
    pa.bi0 = bih[0]; pa.bi1 = bih[1]; pa.bi2 = bih[2]; pa.bi3 = bih[3]; pa.bi4 = bih[4];
    pa.bh0 = bhh[0]; pa.bh1 = bhh[1]; pa.bh2 = bhh[2]; pa.bh3 = bhh[3]; pa.bh4 = bhh[4];
    pa.pre = pre;

    // All recurrent (Whh@h) GEMVs + Wih1@x: ~352 MB weight stream, h from LDS
    k_pre<<<1024, 512, 0, stream>>>(pa);

    // layer 1
    k_cell<<<8, 256, 0, stream>>>(pre, c[0], hn[0], cn[0]);
    k_head<<<256, 256, 0, stream>>>(Wout, bout, hn[0], y);
    // layer 2 (input y1)
    k_gatex<<<2048, 256, 0, stream>>>(Wih[1], y, nullptr, pre + NGATE);
    k_cell<<<8, 256, 0, stream>>>(pre + NGATE, c[1], hn[1], cn[1]);
    k_head<<<256, 256, 0, stream>>>(Wout, bout, hn[1], y + 1024);
    // layer 3 (input y2+y1)
    k_gatex<<<2048, 256, 0, stream>>>(Wih[2], y + 1024, y, pre + 2 * NGATE);
    k_cell<<<8, 256, 0, stream>>>(pre + 2 * NGATE, c[2], hn[2], cn[2]);
    k_head<<<256, 256, 0, stream>>>(Wout, bout, hn[2], y + 2048);
    // layer 4 (input y3+y2)
    k_gatex<<<2048, 256, 0, stream>>>(Wih[3], y + 2048, y + 1024, pre + 3 * NGATE);
    k_cell<<<8, 256, 0, stream>>>(pre + 3 * NGATE, c[3], hn[3], cn[3]);
    k_head<<<256, 256, 0, stream>>>(Wout, bout, hn[3], y + 3072);
    // layer 5 (input y4+y3)
    k_gatex<<<2048, 256, 0, stream>>>(Wih[4], y + 3072, y + 2048, pre + 4 * NGATE);
    k_cell<<<8, 256, 0, stream>>>(pre + 4 * NGATE, c[4], hn[4], cn[4]);
    k_head<<<256, 256, 0, stream>>>(Wout, bout, hn[4], y + 4096);
    // softmax -> out
    k_softmax<<<1, 1024, 0, stream>>>(y + 4096, out);
}